// Round 15
// baseline (387.140 us; speedup 1.0000x reference)
//
#include <hip/hip_runtime.h>

#define NN 100000
#define NE 3200000
#define NG 128
#define HID 64
#define OUTC 128

#define CHUNK 8192
#define NBLK 391                 // ceil(NE / CHUNK)
#define NB1 782                  // ceil(NN / 128) coarse buckets (dst >> 7)

typedef _Float16 half2v __attribute__((ext_vector_type(2)));
typedef _Float16 half4v __attribute__((ext_vector_type(4)));
typedef _Float16 half8v __attribute__((ext_vector_type(8)));
typedef float f32x4 __attribute__((ext_vector_type(4)));

// ---------------- P1: per-block coarse histogram (LDS atomics only) ----------------
__global__ __launch_bounds__(1024) void k_hist(const int* __restrict__ dst,
                                               int* __restrict__ hist1) {
    __shared__ int h[NB1];
    for (int i = threadIdx.x; i < NB1; i += 1024) h[i] = 0;
    __syncthreads();
    int base = blockIdx.x * CHUNK;
    int end = min(base + CHUNK, NE);
    for (int e = base + threadIdx.x; e < end; e += 1024)
        atomicAdd(&h[dst[e] >> 7], 1);
    __syncthreads();
    for (int i = threadIdx.x; i < NB1; i += 1024)
        hist1[i * NBLK + blockIdx.x] = h[i];
}

// ---------------- P2a: per-row totals (one wave per row) ----------------
__global__ __launch_bounds__(256) void k_rowsum(const int* __restrict__ hist1,
                                                int* __restrict__ rowtot) {
    int row = blockIdx.x * 4 + (threadIdx.x >> 6);
    int lane = threadIdx.x & 63;
    if (row >= NB1) return;
    int s = 0;
    for (int k = lane; k < NBLK; k += 64) s += hist1[row * NBLK + k];
#pragma unroll
    for (int m = 1; m < 64; m <<= 1) s += __shfl_xor(s, m);
    if (lane == 0) rowtot[row] = s;
}

// ---------------- P2b: small single-block scan of 782 row totals ----------------
__global__ __launch_bounds__(1024) void k_scanb(const int* __restrict__ rowtot,
                                                int* __restrict__ rowbase,
                                                int* __restrict__ bb) {
    __shared__ int sums[1024];
    int t = threadIdx.x;
    int v = (t < NB1) ? rowtot[t] : 0;
    sums[t] = v;
    __syncthreads();
    for (int d = 1; d < 1024; d <<= 1) {
        int u = (t >= d) ? sums[t - d] : 0;
        __syncthreads();
        sums[t] += u;
        __syncthreads();
    }
    if (t < NB1) {
        int base = sums[t] - v;   // exclusive
        rowbase[t] = base;
        bb[t] = base;
    }
    if (t == 0) bb[NB1] = NE;
}

// ---------------- P2c: per-row exclusive scan (one wave per row) ----------------
__global__ __launch_bounds__(256) void k_rowscan(int* __restrict__ hist1,
                                                 const int* __restrict__ rowbase) {
    int row = blockIdx.x * 4 + (threadIdx.x >> 6);
    int lane = threadIdx.x & 63;
    if (row >= NB1) return;
    int carry = rowbase[row];
    for (int k0 = 0; k0 < NBLK; k0 += 64) {
        int k = k0 + lane;
        int v = (k < NBLK) ? hist1[row * NBLK + k] : 0;
        int xv = v;
#pragma unroll
        for (int m = 1; m < 64; m <<= 1) {
            int y = __shfl_up(xv, m);
            if (lane >= m) xv += y;
        }
        int tot = __shfl(xv, 63);
        if (k < NBLK) hist1[row * NBLK + k] = xv - v + carry;
        carry += tot;
    }
}

// ---------------- P3: LDS counting-sort per chunk + ordered run flush ----------------
// Eliminates scattered 4B global stores (write-allocate amplification): each
// bucket's entries for this block are written as one contiguous run.
__global__ __launch_bounds__(1024) void k_scat(const int* __restrict__ src,
                                               const int* __restrict__ dst,
                                               const int* __restrict__ hist1,
                                               int* __restrict__ packed) {
    __shared__ int bcnt[NB1];
    __shared__ int lbase[NB1];
    __shared__ int lcur[NB1];
    __shared__ int gofs[NB1];
    __shared__ int ssum[1024];
    __shared__ int pk[CHUNK];          // 32 KiB
    int t = threadIdx.x;
    for (int i = t; i < NB1; i += 1024) bcnt[i] = 0;
    __syncthreads();
    int base = blockIdx.x * CHUNK;
    int end = min(base + CHUNK, NE);
    int total = end - base;
    for (int e = base + t; e < end; e += 1024)
        atomicAdd(&bcnt[dst[e] >> 7], 1);
    __syncthreads();
    // block-scan of bcnt -> lbase (exclusive, block-local)
    int v = (t < NB1) ? bcnt[t] : 0;
    ssum[t] = v;
    __syncthreads();
    for (int d = 1; d < 1024; d <<= 1) {
        int u = (t >= d) ? ssum[t - d] : 0;
        __syncthreads();
        ssum[t] += u;
        __syncthreads();
    }
    if (t < NB1) {
        int lb = ssum[t] - v;
        lbase[t] = lb;
        lcur[t] = lb;
        gofs[t] = hist1[t * NBLK + blockIdx.x] - lb;   // global = gofs + local slot
    }
    __syncthreads();
    // scatter into LDS (bucket-grouped)
    for (int e = base + t; e < end; e += 1024) {
        int d = dst[e], s = src[e];
        int slot = atomicAdd(&lcur[d >> 7], 1);
        pk[slot] = ((d & 127) << 17) | s;   // src < 2^17
    }
    __syncthreads();
    // flush: one bucket per thread, contiguous run
    if (t < NB1) {
        int b0 = lbase[t];
        int b1 = (t == NB1 - 1) ? total : lbase[t + 1];
        int go = gofs[t];
        for (int k = b0; k < b1; ++k)
            packed[go + k] = pk[k];
    }
}

// ---------------- P4: within-bucket group by exact dst + FUSED layer-1 ----------------
// Groups neigh by node, writes off, and computes layer 1 (d=3 mean-agg +
// transform + relu -> fp16) for the bucket's 128 nodes in-block.
__global__ __launch_bounds__(512) void k_bucket(const int* __restrict__ packed,
                                                const int* __restrict__ bb,
                                                const float* __restrict__ x,
                                                const float* __restrict__ Wl,
                                                const float* __restrict__ bl,
                                                const float* __restrict__ Wr,
                                                int* __restrict__ neigh,
                                                int* __restrict__ off,
                                                _Float16* __restrict__ hA) {
    int b = blockIdx.x;
    int lo = bb[b], hi = bb[b + 1];
    __shared__ int cnt[128];
    __shared__ int pos[128];
    __shared__ int cur2[128];
    __shared__ float agg3[128][3];
    __shared__ float Wst[448];         // Wl(192) | Wr(192) | bl(64)
    int t = threadIdx.x;
    if (t < 128) cnt[t] = 0;
    if (t < 384) agg3[t / 3][t % 3] = 0.f;   // zero 384 floats
    else if (t < 384 + 64) { }               // (covered below)
    if (t >= 128 && t < 128 + 384) {
        int i = t - 128;                     // second zeroing path not needed; keep simple
    }
    // zero agg3 fully (384 floats) with first 384 threads
    if (t < 384) ((float*)agg3)[t] = 0.f;
    // stage weights
    if (t < 192) Wst[t] = Wl[t];
    else if (t < 384) Wst[t] = Wr[t - 192];
    else if (t < 448) Wst[t] = bl[t - 384];
    __syncthreads();
    // pass 1: count + d=3 feature accumulation (x is L2-resident, 1.2 MB)
    for (int i = lo + t; i < hi; i += 512) {
        int p = packed[i];
        int j = p >> 17;
        int s = p & 0x1FFFF;
        atomicAdd(&cnt[j], 1);
        atomicAdd(&agg3[j][0], x[s * 3 + 0]);
        atomicAdd(&agg3[j][1], x[s * 3 + 1]);
        atomicAdd(&agg3[j][2], x[s * 3 + 2]);
    }
    __syncthreads();
    if (t == 0) {
        int run = lo;
        for (int j = 0; j < 128; ++j) { pos[j] = run; run += cnt[j]; }
    }
    __syncthreads();
    if (t < 128) {
        int node = b * 128 + t;
        if (node <= NN) off[node] = pos[t];
        cur2[t] = pos[t];
    }
    __syncthreads();
    // pass 2: scatter neigh grouped by exact node
    for (int i = lo + t; i < hi; i += 512) {
        int p = packed[i];
        int j = p >> 17;
        int q = atomicAdd(&cur2[j], 1);
        neigh[q] = p & 0x1FFFF;
    }
    // layer-1 transform: node j = t>>2, cols (t&3)*16 .. +16
    {
        int j = t >> 2;
        int c0 = (t & 3) << 4;
        int gn = b * 128 + j;
        if (gn < NN) {
            float ic = 1.0f / fmaxf((float)cnt[j], 1.0f);
            float m0 = agg3[j][0] * ic, m1 = agg3[j][1] * ic, m2 = agg3[j][2] * ic;
            float x0 = x[gn * 3 + 0], x1 = x[gn * 3 + 1], x2 = x[gn * 3 + 2];
            _Float16 outv[16];
#pragma unroll
            for (int cc = 0; cc < 16; ++cc) {
                int c = c0 + cc;
                float acc = Wst[384 + c]
                          + m0 * Wst[0 * 64 + c] + m1 * Wst[1 * 64 + c] + m2 * Wst[2 * 64 + c]
                          + x0 * Wst[192 + 0 * 64 + c] + x1 * Wst[192 + 1 * 64 + c]
                          + x2 * Wst[192 + 2 * 64 + c];
                outv[cc] = (_Float16)fmaxf(acc, 0.0f);
            }
            *(half8v*)&hA[(size_t)gn * 64 + c0] = *(half8v*)&outv[0];
            *(half8v*)&hA[(size_t)gn * 64 + c0 + 8] = *(half8v*)&outv[8];
        }
    }
}

// ---------------- gather-only: quad-mode CSR mean (fp16 in/out) ----------------
__global__ __launch_bounds__(512, 8) void k_agg(const int* __restrict__ off,
                                                const int* __restrict__ neigh,
                                                const _Float16* __restrict__ h,
                                                _Float16* __restrict__ mean) {
    int li = threadIdx.x >> 6;
    int lane = threadIdx.x & 63;
    int g = lane >> 4;                    // neighbor slot within quad
    int q = lane & 15;                    // column quad (cols 4q..4q+3)
    int n = blockIdx.x * 8 + li;          // grid exact: 12500*8 = NN
    if (n >= NN) return;

    int lo = __builtin_amdgcn_readfirstlane(off[n]);
    int hi = __builtin_amdgcn_readfirstlane(off[n + 1]);
    int deg = hi - lo;
    const int* __restrict__ np = neigh + lo;
    const char* __restrict__ hb = (const char*)h;
    unsigned qoff = (unsigned)q << 3;

    float ax = 0.f, ay = 0.f, az = 0.f, aw = 0.f;
    int nq = deg >> 2;
#pragma unroll 4
    for (int i = 0; i < nq; ++i) {
        int s0 = np[4 * i + 0];           // uniform -> s_load
        int s1 = np[4 * i + 1];
        int s2 = np[4 * i + 2];
        int s3 = np[4 * i + 3];
        int s = (g & 2) ? ((g & 1) ? s3 : s2) : ((g & 1) ? s1 : s0);
        half4v v = *(const half4v*)(hb + (((unsigned)s << 7) | qoff));
        ax += (float)v.x; ay += (float)v.y; az += (float)v.z; aw += (float)v.w;
    }
    if (g == 0) {                         // tail: group 0 only
        for (int i = nq << 2; i < deg; ++i) {
            int s = np[i];
            half4v v = *(const half4v*)(hb + (((unsigned)s << 7) | qoff));
            ax += (float)v.x; ay += (float)v.y; az += (float)v.z; aw += (float)v.w;
        }
    }
#pragma unroll
    for (int m = 16; m <= 32; m <<= 1) {
        ax += __shfl_xor(ax, m);
        ay += __shfl_xor(ay, m);
        az += __shfl_xor(az, m);
        aw += __shfl_xor(aw, m);
    }
    if (g == 0) {
        float ic = 1.0f / fmaxf((float)deg, 1.0f);
        *(half4v*)&mean[(size_t)n * 64 + 4 * q] =
            half4v{(_Float16)(ax * ic), (_Float16)(ay * ic),
                   (_Float16)(az * ic), (_Float16)(aw * ic)};
    }
}

// ---------------- transform: [128 nodes][128]=[mean|root] x [128][64] via MFMA ----------------
__global__ __launch_bounds__(512) void k_xform(const _Float16* __restrict__ mean,
                                               const _Float16* __restrict__ h,
                                               const float* __restrict__ Wl,
                                               const float* __restrict__ bl,
                                               const float* __restrict__ Wr,
                                               _Float16* __restrict__ out) {
    __shared__ __align__(16) _Float16 A[128][136];   // 34.8 KiB, padded rows
    __shared__ __align__(16) _Float16 Wt[64][136];   // 17.4 KiB: W^T [c][kk], padded

    const int tid  = threadIdx.x;
    const int li   = tid >> 6;
    const int lane = tid & 63;
    const int g    = lane >> 4;
    const int q    = lane & 15;
    const int nb   = blockIdx.x * 128;

    // ---- stage Wt = [Wl;Wr]^T as f16 (coalesced f32 reads, once per block) ----
    for (int i = tid; i < 8192; i += 512) {
        int kk = i >> 6;       // 0..127
        int c  = i & 63;
        float w = (kk < 64) ? Wl[kk * 64 + c] : Wr[(kk - 64) * 64 + c];
        Wt[c][kk] = (_Float16)w;
    }

    // ---- stage A: thread t -> node tid>>2, 64B chunk tid&3 (mean|mean|root|root) ----
    {
        int n = tid >> 2, c = tid & 3;
        int gn = nb + n;
        if (gn >= NN) gn = NN - 1;                   // clamp (rows unused)
        const _Float16* srcp = (c < 2) ? &mean[(size_t)gn * 64 + (c & 1) * 32]
                                       : &h[(size_t)gn * 64 + (c & 1) * 32];
        half8v v0 = *(const half8v*)(srcp + 0);
        half8v v1 = *(const half8v*)(srcp + 8);
        half8v v2 = *(const half8v*)(srcp + 16);
        half8v v3 = *(const half8v*)(srcp + 24);
        _Float16* dstp = &A[n][(c >> 1) * 64 + (c & 1) * 32];
        *(half8v*)(dstp + 0)  = v0;
        *(half8v*)(dstp + 8)  = v1;
        *(half8v*)(dstp + 16) = v2;
        *(half8v*)(dstp + 24) = v3;
    }
    __syncthreads();

    // ---- B-frags from LDS: lane(g,q) tile t step s -> Wt[16t+q][32s+8g..+8] ----
    half8v bfr[4][4];
    float bias[4];
#pragma unroll
    for (int t = 0; t < 4; ++t) {
        bias[t] = bl[16 * t + q];
#pragma unroll
        for (int s = 0; s < 4; ++s)
            bfr[t][s] = *(const half8v*)&Wt[16 * t + q][32 * s + 8 * g];
    }

    // ---- A-frags: m = q (row 16*li+q), k = 32s + 8g + e ----
    const int row = 16 * li + q;
    half8v a0 = *(const half8v*)&A[row][0 * 32 + 8 * g];
    half8v a1 = *(const half8v*)&A[row][1 * 32 + 8 * g];
    half8v a2 = *(const half8v*)&A[row][2 * 32 + 8 * g];
    half8v a3 = *(const half8v*)&A[row][3 * 32 + 8 * g];

    f32x4 acc[4];
#pragma unroll
    for (int t = 0; t < 4; ++t) {
        acc[t] = f32x4{0.f, 0.f, 0.f, 0.f};
        acc[t] = __builtin_amdgcn_mfma_f32_16x16x32_f16(a0, bfr[t][0], acc[t], 0, 0, 0);
        acc[t] = __builtin_amdgcn_mfma_f32_16x16x32_f16(a1, bfr[t][1], acc[t], 0, 0, 0);
        acc[t] = __builtin_amdgcn_mfma_f32_16x16x32_f16(a2, bfr[t][2], acc[t], 0, 0, 0);
        acc[t] = __builtin_amdgcn_mfma_f32_16x16x32_f16(a3, bfr[t][3], acc[t], 0, 0, 0);
    }

    // ---- epilogue: C row (node) = g*4+r, col = 16t+q; bias + relu + fp16 store ----
#pragma unroll
    for (int t = 0; t < 4; ++t) {
        int col = 16 * t + q;
#pragma unroll
        for (int r = 0; r < 4; ++r) {
            int gn = nb + 16 * li + g * 4 + r;
            if (gn < NN) {
                float val = acc[t][r] + bias[t];
                out[(size_t)gn * 64 + col] = (_Float16)fmaxf(val, 0.0f);
            }
        }
    }
}

// ---------------- pooling helpers ----------------
__device__ __forceinline__ int lower_bound_batch(const int* __restrict__ batch, int val) {
    int lo = 0, hi = NN;
    while (lo < hi) {
        int mid = (lo + hi) >> 1;
        if (batch[mid] < val) lo = mid + 1; else hi = mid;
    }
    return lo;
}

__global__ __launch_bounds__(64) void k_pool(const _Float16* __restrict__ h,
                                             const int* __restrict__ batch,
                                             float* __restrict__ psum) {
    int g = blockIdx.x >> 3;
    int part = blockIdx.x & 7;
    int lane = threadIdx.x;
    int lo = lower_bound_batch(batch, g);
    int hi = lower_bound_batch(batch, g + 1);
    float s = 0.0f;
    for (int n = lo + part; n < hi; n += 8) s += (float)h[(size_t)n * 64 + lane];
    atomicAdd(&psum[g * 64 + lane], s);
}

__global__ __launch_bounds__(128) void k_fc(const float* __restrict__ psum,
                                            const int* __restrict__ batch,
                                            const float* __restrict__ Wfc,
                                            const float* __restrict__ bfc,
                                            float* __restrict__ out) {
    __shared__ float meanv[64];
    __shared__ float red[2];
    int g = blockIdx.x;
    int c = threadIdx.x;
    int lo = lower_bound_batch(batch, g);
    int hi = lower_bound_batch(batch, g + 1);
    float icnt = 1.0f / fmaxf((float)(hi - lo), 1.0f);
    if (c < 64) meanv[c] = psum[g * 64 + c] * icnt;
    __syncthreads();
    float acc = bfc[c];
#pragma unroll
    for (int k = 0; k < 64; ++k) acc += meanv[k] * Wfc[k * 128 + c];
    float ss = acc * acc;
#pragma unroll
    for (int off = 32; off; off >>= 1) ss += __shfl_down(ss, off);
    if ((c & 63) == 0) red[c >> 6] = ss;
    __syncthreads();
    float norm = fmaxf(sqrtf(red[0] + red[1]), 1e-12f);
    out[g * 128 + c] = acc / norm;
}

extern "C" void kernel_launch(void* const* d_in, const int* in_sizes, int n_in,
                              void* d_out, int out_size, void* d_ws, size_t ws_size,
                              hipStream_t stream) {
    const float* x    = (const float*)d_in[0];
    const int*   ei   = (const int*)d_in[1];
    const int*   src  = ei;
    const int*   dst  = ei + NE;
    const int*   batch = (const int*)d_in[2];
    const float* Wl1 = (const float*)d_in[3];
    const float* bl1 = (const float*)d_in[4];
    const float* Wr1 = (const float*)d_in[5];
    const float* Wl2 = (const float*)d_in[6];
    const float* bl2 = (const float*)d_in[7];
    const float* Wr2 = (const float*)d_in[8];
    const float* Wl3 = (const float*)d_in[9];
    const float* bl3 = (const float*)d_in[10];
    const float* Wr3 = (const float*)d_in[11];
    const float* Wl4 = (const float*)d_in[12];
    const float* bl4 = (const float*)d_in[13];
    const float* Wr4 = (const float*)d_in[14];
    const float* Wfc = (const float*)d_in[15];
    const float* bfc = (const float*)d_in[16];
    float* out = (float*)d_out;

    // workspace layout
    _Float16* hA   = (_Float16*)d_ws;                 // [N,64] fp16
    _Float16* hB   = hA + (size_t)NN * 64;            // [N,64] fp16
    _Float16* mnb  = hB + (size_t)NN * 64;            // [N,64] fp16 mean buffer
    float* psum    = (float*)(mnb + (size_t)NN * 64); // [G,64]
    int*   off     = (int*)(psum + (size_t)NG * 64);  // [N+1]
    int*   bb      = off + NN + 1;                    // [NB1+1]
    int*   rowtot  = bb + NB1 + 1;                    // [NB1]
    int*   rowbase = rowtot + NB1;                    // [NB1]
    int*   hist1   = rowbase + NB1;                   // [NB1*NBLK]
    int*   packed  = hist1 + NB1 * NBLK;              // [E]
    int*   neigh   = packed + NE;                     // [E]

    hipMemsetAsync(psum, 0, (size_t)NG * 64 * sizeof(float), stream);

    // CSR build: atomic-free two-level bucket sort, fully parallel scan
    k_hist<<<NBLK, 1024, 0, stream>>>(dst, hist1);
    k_rowsum<<<(NB1 + 3) / 4, 256, 0, stream>>>(hist1, rowtot);
    k_scanb<<<1, 1024, 0, stream>>>(rowtot, rowbase, bb);
    k_rowscan<<<(NB1 + 3) / 4, 256, 0, stream>>>(hist1, rowbase);
    k_scat<<<NBLK, 1024, 0, stream>>>(src, dst, hist1, packed);
    // bucket grouping + fused layer 1
    k_bucket<<<NB1, 512, 0, stream>>>(packed, bb, x, Wl1, bl1, Wr1, neigh, off, hA);

    const int aggGrid = (NN + 7) / 8;
    const int xfGrid  = (NN + 127) / 128;

    // layers 2-4: gather-only + MFMA transform (ping-pong hA/hB)
    k_agg<<<aggGrid, 512, 0, stream>>>(off, neigh, hA, mnb);
    k_xform<<<xfGrid, 512, 0, stream>>>(mnb, hA, Wl2, bl2, Wr2, hB);

    k_agg<<<aggGrid, 512, 0, stream>>>(off, neigh, hB, mnb);
    k_xform<<<xfGrid, 512, 0, stream>>>(mnb, hB, Wl3, bl3, Wr3, hA);

    k_agg<<<aggGrid, 512, 0, stream>>>(off, neigh, hA, mnb);
    k_xform<<<xfGrid, 512, 0, stream>>>(mnb, hA, Wl4, bl4, Wr4, hB);

    k_pool<<<NG * 8, 64, 0, stream>>>(hB, batch, psum);
    k_fc<<<NG, 128, 0, stream>>>(psum, batch, Wfc, bfc, out);
}

// Round 16
// 354.902 us; speedup vs baseline: 1.0908x; 1.0908x over previous
//
#include <hip/hip_runtime.h>

#define NN 100000
#define NE 3200000
#define NG 128
#define HID 64
#define OUTC 128

#define CHUNK 8192
#define NBLK 391                 // ceil(NE / CHUNK)
#define NB1 782                  // ceil(NN / 128) coarse buckets (dst >> 7)

typedef _Float16 half2v __attribute__((ext_vector_type(2)));
typedef _Float16 half4v __attribute__((ext_vector_type(4)));
typedef _Float16 half8v __attribute__((ext_vector_type(8)));
typedef float f32x4 __attribute__((ext_vector_type(4)));

// ---------------- P1: per-block coarse histogram (LDS atomics only) ----------------
__global__ __launch_bounds__(1024) void k_hist(const int* __restrict__ dst,
                                               int* __restrict__ hist1) {
    __shared__ int h[NB1];
    for (int i = threadIdx.x; i < NB1; i += 1024) h[i] = 0;
    __syncthreads();
    int base = blockIdx.x * CHUNK;
    int end = min(base + CHUNK, NE);
    for (int e = base + threadIdx.x; e < end; e += 1024)
        atomicAdd(&h[dst[e] >> 7], 1);
    __syncthreads();
    for (int i = threadIdx.x; i < NB1; i += 1024)
        hist1[i * NBLK + blockIdx.x] = h[i];
}

// ---------------- P2a: per-row totals (one wave per row) ----------------
__global__ __launch_bounds__(256) void k_rowsum(const int* __restrict__ hist1,
                                                int* __restrict__ rowtot) {
    int row = blockIdx.x * 4 + (threadIdx.x >> 6);
    int lane = threadIdx.x & 63;
    if (row >= NB1) return;
    int s = 0;
    for (int k = lane; k < NBLK; k += 64) s += hist1[row * NBLK + k];
#pragma unroll
    for (int m = 1; m < 64; m <<= 1) s += __shfl_xor(s, m);
    if (lane == 0) rowtot[row] = s;
}

// ---------------- P2b: small single-block scan of 782 row totals ----------------
__global__ __launch_bounds__(1024) void k_scanb(const int* __restrict__ rowtot,
                                                int* __restrict__ rowbase,
                                                int* __restrict__ bb) {
    __shared__ int sums[1024];
    int t = threadIdx.x;
    int v = (t < NB1) ? rowtot[t] : 0;
    sums[t] = v;
    __syncthreads();
    for (int d = 1; d < 1024; d <<= 1) {
        int u = (t >= d) ? sums[t - d] : 0;
        __syncthreads();
        sums[t] += u;
        __syncthreads();
    }
    if (t < NB1) {
        int base = sums[t] - v;   // exclusive
        rowbase[t] = base;
        bb[t] = base;
    }
    if (t == 0) bb[NB1] = NE;
}

// ---------------- P2c: per-row exclusive scan (one wave per row) ----------------
__global__ __launch_bounds__(256) void k_rowscan(int* __restrict__ hist1,
                                                 const int* __restrict__ rowbase) {
    int row = blockIdx.x * 4 + (threadIdx.x >> 6);
    int lane = threadIdx.x & 63;
    if (row >= NB1) return;
    int carry = rowbase[row];
    for (int k0 = 0; k0 < NBLK; k0 += 64) {
        int k = k0 + lane;
        int v = (k < NBLK) ? hist1[row * NBLK + k] : 0;
        int xv = v;
#pragma unroll
        for (int m = 1; m < 64; m <<= 1) {
            int y = __shfl_up(xv, m);
            if (lane >= m) xv += y;
        }
        int tot = __shfl(xv, 63);
        if (k < NBLK) hist1[row * NBLK + k] = xv - v + carry;
        carry += tot;
    }
}

// ---------------- P3: LDS counting-sort per chunk + ordered run flush ----------------
__global__ __launch_bounds__(1024) void k_scat(const int* __restrict__ src,
                                               const int* __restrict__ dst,
                                               const int* __restrict__ hist1,
                                               int* __restrict__ packed) {
    __shared__ int bcnt[NB1];
    __shared__ int lbase[NB1];
    __shared__ int lcur[NB1];
    __shared__ int gofs[NB1];
    __shared__ int ssum[1024];
    __shared__ int pk[CHUNK];          // 32 KiB
    int t = threadIdx.x;
    for (int i = t; i < NB1; i += 1024) bcnt[i] = 0;
    __syncthreads();
    int base = blockIdx.x * CHUNK;
    int end = min(base + CHUNK, NE);
    int total = end - base;
    for (int e = base + t; e < end; e += 1024)
        atomicAdd(&bcnt[dst[e] >> 7], 1);
    __syncthreads();
    int v = (t < NB1) ? bcnt[t] : 0;
    ssum[t] = v;
    __syncthreads();
    for (int d = 1; d < 1024; d <<= 1) {
        int u = (t >= d) ? ssum[t - d] : 0;
        __syncthreads();
        ssum[t] += u;
        __syncthreads();
    }
    if (t < NB1) {
        int lb = ssum[t] - v;
        lbase[t] = lb;
        lcur[t] = lb;
        gofs[t] = hist1[t * NBLK + blockIdx.x] - lb;   // global = gofs + local slot
    }
    __syncthreads();
    for (int e = base + t; e < end; e += 1024) {
        int d = dst[e], s = src[e];
        int slot = atomicAdd(&lcur[d >> 7], 1);
        pk[slot] = ((d & 127) << 17) | s;   // src < 2^17
    }
    __syncthreads();
    if (t < NB1) {
        int b0 = lbase[t];
        int b1 = (t == NB1 - 1) ? total : lbase[t + 1];
        int go = gofs[t];
        for (int k = b0; k < b1; ++k)
            packed[go + k] = pk[k];
    }
}

// ---------------- P4: within-bucket group by exact dst; emit neigh + off ----------------
__global__ __launch_bounds__(512) void k_bucket(const int* __restrict__ packed,
                                                const int* __restrict__ bb,
                                                int* __restrict__ neigh,
                                                int* __restrict__ off) {
    int b = blockIdx.x;
    int lo = bb[b], hi = bb[b + 1];
    __shared__ int cnt[128];
    __shared__ int pos[128];
    __shared__ int cur2[128];
    if (threadIdx.x < 128) cnt[threadIdx.x] = 0;
    __syncthreads();
    for (int i = lo + threadIdx.x; i < hi; i += 512)
        atomicAdd(&cnt[packed[i] >> 17], 1);
    __syncthreads();
    if (threadIdx.x == 0) {
        int run = lo;
        for (int j = 0; j < 128; ++j) { pos[j] = run; run += cnt[j]; }
    }
    __syncthreads();
    if (threadIdx.x < 128) {
        int node = b * 128 + threadIdx.x;
        if (node <= NN) off[node] = pos[threadIdx.x];
        cur2[threadIdx.x] = pos[threadIdx.x];
    }
    __syncthreads();
    for (int i = lo + threadIdx.x; i < hi; i += 512) {
        int p = packed[i];
        int j = p >> 17;
        int q = atomicAdd(&cur2[j], 1);
        neigh[q] = p & 0x1FFFF;
    }
}

// ---------------- layer 1: CSR mean-agg (d=3) + transform, fp16 out ----------------
__global__ __launch_bounds__(256) void k_l1(const int* __restrict__ off,
                                            const int* __restrict__ neigh,
                                            const float* __restrict__ x,
                                            const float* __restrict__ Wl,
                                            const float* __restrict__ bl,
                                            const float* __restrict__ Wr,
                                            _Float16* __restrict__ out) {
    int n = blockIdx.x * 4 + (threadIdx.x >> 6);
    int c = threadIdx.x & 63;
    if (n >= NN) return;
    int lo = off[n], hi = off[n + 1];
    float a0 = 0.f, a1 = 0.f, a2 = 0.f;
    for (int i = lo + c; i < hi; i += 64) {
        int s = neigh[i];
        a0 += x[s * 3 + 0];
        a1 += x[s * 3 + 1];
        a2 += x[s * 3 + 2];
    }
#pragma unroll
    for (int m = 1; m < 64; m <<= 1) {
        a0 += __shfl_xor(a0, m);
        a1 += __shfl_xor(a1, m);
        a2 += __shfl_xor(a2, m);
    }
    float ic = 1.0f / fmaxf((float)(hi - lo), 1.0f);
    a0 *= ic; a1 *= ic; a2 *= ic;
    float x0 = x[n * 3 + 0], x1 = x[n * 3 + 1], x2 = x[n * 3 + 2];
    float acc = bl[c]
              + a0 * Wl[0 * 64 + c] + a1 * Wl[1 * 64 + c] + a2 * Wl[2 * 64 + c]
              + x0 * Wr[0 * 64 + c] + x1 * Wr[1 * 64 + c] + x2 * Wr[2 * 64 + c];
    out[(size_t)n * 64 + c] = (_Float16)fmaxf(acc, 0.0f);
}

// ---------------- gather-only: quad-mode CSR mean (fp16 in/out) ----------------
__global__ __launch_bounds__(512, 8) void k_agg(const int* __restrict__ off,
                                                const int* __restrict__ neigh,
                                                const _Float16* __restrict__ h,
                                                _Float16* __restrict__ mean) {
    int li = threadIdx.x >> 6;
    int lane = threadIdx.x & 63;
    int g = lane >> 4;                    // neighbor slot within quad
    int q = lane & 15;                    // column quad (cols 4q..4q+3)
    int n = blockIdx.x * 8 + li;          // grid exact: 12500*8 = NN
    if (n >= NN) return;

    int lo = __builtin_amdgcn_readfirstlane(off[n]);
    int hi = __builtin_amdgcn_readfirstlane(off[n + 1]);
    int deg = hi - lo;
    const int* __restrict__ np = neigh + lo;
    const char* __restrict__ hb = (const char*)h;
    unsigned qoff = (unsigned)q << 3;

    float ax = 0.f, ay = 0.f, az = 0.f, aw = 0.f;
    int nq = deg >> 2;
#pragma unroll 4
    for (int i = 0; i < nq; ++i) {
        int s0 = np[4 * i + 0];           // uniform -> s_load
        int s1 = np[4 * i + 1];
        int s2 = np[4 * i + 2];
        int s3 = np[4 * i + 3];
        int s = (g & 2) ? ((g & 1) ? s3 : s2) : ((g & 1) ? s1 : s0);
        half4v v = *(const half4v*)(hb + (((unsigned)s << 7) | qoff));
        ax += (float)v.x; ay += (float)v.y; az += (float)v.z; aw += (float)v.w;
    }
    if (g == 0) {                         // tail: group 0 only
        for (int i = nq << 2; i < deg; ++i) {
            int s = np[i];
            half4v v = *(const half4v*)(hb + (((unsigned)s << 7) | qoff));
            ax += (float)v.x; ay += (float)v.y; az += (float)v.z; aw += (float)v.w;
        }
    }
#pragma unroll
    for (int m = 16; m <= 32; m <<= 1) {
        ax += __shfl_xor(ax, m);
        ay += __shfl_xor(ay, m);
        az += __shfl_xor(az, m);
        aw += __shfl_xor(aw, m);
    }
    if (g == 0) {
        float ic = 1.0f / fmaxf((float)deg, 1.0f);
        *(half4v*)&mean[(size_t)n * 64 + 4 * q] =
            half4v{(_Float16)(ax * ic), (_Float16)(ay * ic),
                   (_Float16)(az * ic), (_Float16)(aw * ic)};
    }
}

// ---------------- transform: [128 nodes][128]=[mean|root] x [128][64] via MFMA ----------------
__global__ __launch_bounds__(512) void k_xform(const _Float16* __restrict__ mean,
                                               const _Float16* __restrict__ h,
                                               const float* __restrict__ Wl,
                                               const float* __restrict__ bl,
                                               const float* __restrict__ Wr,
                                               _Float16* __restrict__ out) {
    __shared__ __align__(16) _Float16 A[128][136];   // 34.8 KiB, padded rows
    __shared__ __align__(16) _Float16 Wt[64][136];   // 17.4 KiB: W^T [c][kk], padded

    const int tid  = threadIdx.x;
    const int li   = tid >> 6;
    const int lane = tid & 63;
    const int g    = lane >> 4;
    const int q    = lane & 15;
    const int nb   = blockIdx.x * 128;

    // ---- stage Wt = [Wl;Wr]^T as f16 (coalesced f32 reads, once per block) ----
    for (int i = tid; i < 8192; i += 512) {
        int kk = i >> 6;       // 0..127
        int c  = i & 63;
        float w = (kk < 64) ? Wl[kk * 64 + c] : Wr[(kk - 64) * 64 + c];
        Wt[c][kk] = (_Float16)w;
    }

    // ---- stage A: thread t -> node tid>>2, 64B chunk tid&3 (mean|mean|root|root) ----
    {
        int n = tid >> 2, c = tid & 3;
        int gn = nb + n;
        if (gn >= NN) gn = NN - 1;                   // clamp (rows unused)
        const _Float16* srcp = (c < 2) ? &mean[(size_t)gn * 64 + (c & 1) * 32]
                                       : &h[(size_t)gn * 64 + (c & 1) * 32];
        half8v v0 = *(const half8v*)(srcp + 0);
        half8v v1 = *(const half8v*)(srcp + 8);
        half8v v2 = *(const half8v*)(srcp + 16);
        half8v v3 = *(const half8v*)(srcp + 24);
        _Float16* dstp = &A[n][(c >> 1) * 64 + (c & 1) * 32];
        *(half8v*)(dstp + 0)  = v0;
        *(half8v*)(dstp + 8)  = v1;
        *(half8v*)(dstp + 16) = v2;
        *(half8v*)(dstp + 24) = v3;
    }
    __syncthreads();

    // ---- B-frags from LDS: lane(g,q) tile t step s -> Wt[16t+q][32s+8g..+8] ----
    half8v bfr[4][4];
    float bias[4];
#pragma unroll
    for (int t = 0; t < 4; ++t) {
        bias[t] = bl[16 * t + q];
#pragma unroll
        for (int s = 0; s < 4; ++s)
            bfr[t][s] = *(const half8v*)&Wt[16 * t + q][32 * s + 8 * g];
    }

    // ---- A-frags: m = q (row 16*li+q), k = 32s + 8g + e ----
    const int row = 16 * li + q;
    half8v a0 = *(const half8v*)&A[row][0 * 32 + 8 * g];
    half8v a1 = *(const half8v*)&A[row][1 * 32 + 8 * g];
    half8v a2 = *(const half8v*)&A[row][2 * 32 + 8 * g];
    half8v a3 = *(const half8v*)&A[row][3 * 32 + 8 * g];

    f32x4 acc[4];
#pragma unroll
    for (int t = 0; t < 4; ++t) {
        acc[t] = f32x4{0.f, 0.f, 0.f, 0.f};
        acc[t] = __builtin_amdgcn_mfma_f32_16x16x32_f16(a0, bfr[t][0], acc[t], 0, 0, 0);
        acc[t] = __builtin_amdgcn_mfma_f32_16x16x32_f16(a1, bfr[t][1], acc[t], 0, 0, 0);
        acc[t] = __builtin_amdgcn_mfma_f32_16x16x32_f16(a2, bfr[t][2], acc[t], 0, 0, 0);
        acc[t] = __builtin_amdgcn_mfma_f32_16x16x32_f16(a3, bfr[t][3], acc[t], 0, 0, 0);
    }

    // ---- epilogue: C row (node) = g*4+r, col = 16t+q; bias + relu + fp16 store ----
#pragma unroll
    for (int t = 0; t < 4; ++t) {
        int col = 16 * t + q;
#pragma unroll
        for (int r = 0; r < 4; ++r) {
            int gn = nb + 16 * li + g * 4 + r;
            if (gn < NN) {
                float val = acc[t][r] + bias[t];
                out[(size_t)gn * 64 + col] = (_Float16)fmaxf(val, 0.0f);
            }
        }
    }
}

// ---------------- pooling helpers ----------------
__device__ __forceinline__ int lower_bound_batch(const int* __restrict__ batch, int val) {
    int lo = 0, hi = NN;
    while (lo < hi) {
        int mid = (lo + hi) >> 1;
        if (batch[mid] < val) lo = mid + 1; else hi = mid;
    }
    return lo;
}

__global__ __launch_bounds__(64) void k_pool(const _Float16* __restrict__ h,
                                             const int* __restrict__ batch,
                                             float* __restrict__ psum) {
    int g = blockIdx.x >> 3;
    int part = blockIdx.x & 7;
    int lane = threadIdx.x;
    int lo = lower_bound_batch(batch, g);
    int hi = lower_bound_batch(batch, g + 1);
    float s = 0.0f;
    for (int n = lo + part; n < hi; n += 8) s += (float)h[(size_t)n * 64 + lane];
    atomicAdd(&psum[g * 64 + lane], s);
}

__global__ __launch_bounds__(128) void k_fc(const float* __restrict__ psum,
                                            const int* __restrict__ batch,
                                            const float* __restrict__ Wfc,
                                            const float* __restrict__ bfc,
                                            float* __restrict__ out) {
    __shared__ float meanv[64];
    __shared__ float red[2];
    int g = blockIdx.x;
    int c = threadIdx.x;
    int lo = lower_bound_batch(batch, g);
    int hi = lower_bound_batch(batch, g + 1);
    float icnt = 1.0f / fmaxf((float)(hi - lo), 1.0f);
    if (c < 64) meanv[c] = psum[g * 64 + c] * icnt;
    __syncthreads();
    float acc = bfc[c];
#pragma unroll
    for (int k = 0; k < 64; ++k) acc += meanv[k] * Wfc[k * 128 + c];
    float ss = acc * acc;
#pragma unroll
    for (int off = 32; off; off >>= 1) ss += __shfl_down(ss, off);
    if ((c & 63) == 0) red[c >> 6] = ss;
    __syncthreads();
    float norm = fmaxf(sqrtf(red[0] + red[1]), 1e-12f);
    out[g * 128 + c] = acc / norm;
}

extern "C" void kernel_launch(void* const* d_in, const int* in_sizes, int n_in,
                              void* d_out, int out_size, void* d_ws, size_t ws_size,
                              hipStream_t stream) {
    const float* x    = (const float*)d_in[0];
    const int*   ei   = (const int*)d_in[1];
    const int*   src  = ei;
    const int*   dst  = ei + NE;
    const int*   batch = (const int*)d_in[2];
    const float* Wl1 = (const float*)d_in[3];
    const float* bl1 = (const float*)d_in[4];
    const float* Wr1 = (const float*)d_in[5];
    const float* Wl2 = (const float*)d_in[6];
    const float* bl2 = (const float*)d_in[7];
    const float* Wr2 = (const float*)d_in[8];
    const float* Wl3 = (const float*)d_in[9];
    const float* bl3 = (const float*)d_in[10];
    const float* Wr3 = (const float*)d_in[11];
    const float* Wl4 = (const float*)d_in[12];
    const float* bl4 = (const float*)d_in[13];
    const float* Wr4 = (const float*)d_in[14];
    const float* Wfc = (const float*)d_in[15];
    const float* bfc = (const float*)d_in[16];
    float* out = (float*)d_out;

    // workspace layout
    _Float16* hA   = (_Float16*)d_ws;                 // [N,64] fp16
    _Float16* hB   = hA + (size_t)NN * 64;            // [N,64] fp16
    _Float16* mnb  = hB + (size_t)NN * 64;            // [N,64] fp16 mean buffer
    float* psum    = (float*)(mnb + (size_t)NN * 64); // [G,64]
    int*   off     = (int*)(psum + (size_t)NG * 64);  // [N+1]
    int*   bb      = off + NN + 1;                    // [NB1+1]
    int*   rowtot  = bb + NB1 + 1;                    // [NB1]
    int*   rowbase = rowtot + NB1;                    // [NB1]
    int*   hist1   = rowbase + NB1;                   // [NB1*NBLK]
    int*   packed  = hist1 + NB1 * NBLK;              // [E]
    int*   neigh   = packed + NE;                     // [E]

    hipMemsetAsync(psum, 0, (size_t)NG * 64 * sizeof(float), stream);

    // CSR build: atomic-free two-level bucket sort, fully parallel scan
    k_hist<<<NBLK, 1024, 0, stream>>>(dst, hist1);
    k_rowsum<<<(NB1 + 3) / 4, 256, 0, stream>>>(hist1, rowtot);
    k_scanb<<<1, 1024, 0, stream>>>(rowtot, rowbase, bb);
    k_rowscan<<<(NB1 + 3) / 4, 256, 0, stream>>>(hist1, rowbase);
    k_scat<<<NBLK, 1024, 0, stream>>>(src, dst, hist1, packed);
    k_bucket<<<NB1, 512, 0, stream>>>(packed, bb, neigh, off);

    // layer 1 (fused d=3 agg + transform), fp16 out
    k_l1<<<(NN + 3) / 4, 256, 0, stream>>>(off, neigh, x, Wl1, bl1, Wr1, hA);

    const int aggGrid = (NN + 7) / 8;
    const int xfGrid  = (NN + 127) / 128;

    // layers 2-4: gather-only + MFMA transform (ping-pong hA/hB)
    k_agg<<<aggGrid, 512, 0, stream>>>(off, neigh, hA, mnb);
    k_xform<<<xfGrid, 512, 0, stream>>>(mnb, hA, Wl2, bl2, Wr2, hB);

    k_agg<<<aggGrid, 512, 0, stream>>>(off, neigh, hB, mnb);
    k_xform<<<xfGrid, 512, 0, stream>>>(mnb, hB, Wl3, bl3, Wr3, hA);

    k_agg<<<aggGrid, 512, 0, stream>>>(off, neigh, hA, mnb);
    k_xform<<<xfGrid, 512, 0, stream>>>(mnb, hA, Wl4, bl4, Wr4, hB);

    k_pool<<<NG * 8, 64, 0, stream>>>(hB, batch, psum);
    k_fc<<<NG, 128, 0, stream>>>(psum, batch, Wfc, bfc, out);
}

// Round 17
// 334.030 us; speedup vs baseline: 1.1590x; 1.0625x over previous
//
#include <hip/hip_runtime.h>

#define NN 100000
#define NE 3200000
#define NG 128
#define HID 64
#define OUTC 128

#define CHUNK 8192
#define NBLK 391                 // ceil(NE / CHUNK)
#define NB1 782                  // ceil(NN / 128) coarse buckets (dst >> 7)
#define SLCAP 8192               // max edges per coarse bucket (mean 4092, sigma 64)

typedef _Float16 half2v __attribute__((ext_vector_type(2)));
typedef _Float16 half4v __attribute__((ext_vector_type(4)));
typedef _Float16 half8v __attribute__((ext_vector_type(8)));
typedef float f32x4 __attribute__((ext_vector_type(4)));

// ---------------- P1: per-block coarse histogram (LDS atomics only) ----------------
__global__ __launch_bounds__(1024) void k_hist(const int* __restrict__ dst,
                                               int* __restrict__ hist1) {
    __shared__ int h[NB1];
    for (int i = threadIdx.x; i < NB1; i += 1024) h[i] = 0;
    __syncthreads();
    int base = blockIdx.x * CHUNK;
    int end = min(base + CHUNK, NE);
    for (int e = base + threadIdx.x; e < end; e += 1024)
        atomicAdd(&h[dst[e] >> 7], 1);
    __syncthreads();
    for (int i = threadIdx.x; i < NB1; i += 1024)
        hist1[i * NBLK + blockIdx.x] = h[i];
}

// ---------------- P2a: per-row totals (one wave per row) ----------------
__global__ __launch_bounds__(256) void k_rowsum(const int* __restrict__ hist1,
                                                int* __restrict__ rowtot) {
    int row = blockIdx.x * 4 + (threadIdx.x >> 6);
    int lane = threadIdx.x & 63;
    if (row >= NB1) return;
    int s = 0;
    for (int k = lane; k < NBLK; k += 64) s += hist1[row * NBLK + k];
#pragma unroll
    for (int m = 1; m < 64; m <<= 1) s += __shfl_xor(s, m);
    if (lane == 0) rowtot[row] = s;
}

// ---------------- P2b: 13-wave scan of 782 row totals (3 barriers) ----------------
__global__ __launch_bounds__(832) void k_scanb(const int* __restrict__ rowtot,
                                               int* __restrict__ rowbase,
                                               int* __restrict__ bb) {
    __shared__ int wsum[13];
    int t = threadIdx.x;
    int w = t >> 6, l = t & 63;
    int v = (t < NB1) ? rowtot[t] : 0;
    int x = v;
#pragma unroll
    for (int m = 1; m < 64; m <<= 1) {
        int y = __shfl_up(x, m);
        if (l >= m) x += y;
    }
    if (l == 63) wsum[w] = x;
    __syncthreads();
    if (t == 0) {
        int run = 0;
        for (int k = 0; k < 13; ++k) { int u = wsum[k]; wsum[k] = run; run += u; }
    }
    __syncthreads();
    if (t < NB1) {
        int base = wsum[w] + x - v;      // exclusive
        rowbase[t] = base;
        bb[t] = base;
    }
    if (t == 0) bb[NB1] = NE;
}

// ---------------- P2c: per-row exclusive scan (one wave per row) ----------------
__global__ __launch_bounds__(256) void k_rowscan(int* __restrict__ hist1,
                                                 const int* __restrict__ rowbase) {
    int row = blockIdx.x * 4 + (threadIdx.x >> 6);
    int lane = threadIdx.x & 63;
    if (row >= NB1) return;
    int carry = rowbase[row];
    for (int k0 = 0; k0 < NBLK; k0 += 64) {
        int k = k0 + lane;
        int v = (k < NBLK) ? hist1[row * NBLK + k] : 0;
        int xv = v;
#pragma unroll
        for (int m = 1; m < 64; m <<= 1) {
            int y = __shfl_up(xv, m);
            if (lane >= m) xv += y;
        }
        int tot = __shfl(xv, 63);
        if (k < NBLK) hist1[row * NBLK + k] = xv - v + carry;
        carry += tot;
    }
}

// ---------------- P3: LDS counting-sort per chunk + ordered run flush ----------------
__global__ __launch_bounds__(1024) void k_scat(const int* __restrict__ src,
                                               const int* __restrict__ dst,
                                               const int* __restrict__ hist1,
                                               int* __restrict__ packed) {
    __shared__ int bcnt[NB1];
    __shared__ int lbase[NB1];
    __shared__ int lcur[NB1];
    __shared__ int gofs[NB1];
    __shared__ int ssum[1024];
    __shared__ int pk[CHUNK];          // 32 KiB
    int t = threadIdx.x;
    for (int i = t; i < NB1; i += 1024) bcnt[i] = 0;
    __syncthreads();
    int base = blockIdx.x * CHUNK;
    int end = min(base + CHUNK, NE);
    int total = end - base;
    for (int e = base + t; e < end; e += 1024)
        atomicAdd(&bcnt[dst[e] >> 7], 1);
    __syncthreads();
    int v = (t < NB1) ? bcnt[t] : 0;
    ssum[t] = v;
    __syncthreads();
    for (int d = 1; d < 1024; d <<= 1) {
        int u = (t >= d) ? ssum[t - d] : 0;
        __syncthreads();
        ssum[t] += u;
        __syncthreads();
    }
    if (t < NB1) {
        int lb = ssum[t] - v;
        lbase[t] = lb;
        lcur[t] = lb;
        gofs[t] = hist1[t * NBLK + blockIdx.x] - lb;   // global = gofs + local slot
    }
    __syncthreads();
    for (int e = base + t; e < end; e += 1024) {
        int d = dst[e], s = src[e];
        int slot = atomicAdd(&lcur[d >> 7], 1);
        pk[slot] = ((d & 127) << 17) | s;   // src < 2^17
    }
    __syncthreads();
    if (t < NB1) {
        int b0 = lbase[t];
        int b1 = (t == NB1 - 1) ? total : lbase[t + 1];
        int go = gofs[t];
        for (int k = b0; k < b1; ++k)
            packed[go + k] = pk[k];
    }
}

// ---------------- P4: group by exact dst, ONE atomic per edge ----------------
__global__ __launch_bounds__(512) void k_bucket(const int* __restrict__ packed,
                                                const int* __restrict__ bb,
                                                int* __restrict__ neigh,
                                                int* __restrict__ off) {
    int b = blockIdx.x;
    int lo = bb[b], hi = bb[b + 1];
    __shared__ int cnt[128];
    __shared__ int pos[128];
    __shared__ unsigned short sl[SLCAP];   // 16 KiB slot table
    int t = threadIdx.x;
    if (t < 128) cnt[t] = 0;
    __syncthreads();
    // pass 1: slot assignment (single atomic per edge)
    for (int i = lo + t; i < hi; i += 512) {
        int p = packed[i];
        int j = p >> 17;
        int s = atomicAdd(&cnt[j], 1);
        sl[i - lo] = (unsigned short)s;
    }
    __syncthreads();
    // scan 128 counters with wave 0 (two 64-wide wave scans)
    if (t < 64) {
        int v0 = cnt[t], v1 = cnt[64 + t];
        int x0 = v0;
#pragma unroll
        for (int m = 1; m < 64; m <<= 1) { int y = __shfl_up(x0, m); if (t >= m) x0 += y; }
        int tot0 = __shfl(x0, 63);
        int x1 = v1;
#pragma unroll
        for (int m = 1; m < 64; m <<= 1) { int y = __shfl_up(x1, m); if (t >= m) x1 += y; }
        pos[t] = lo + x0 - v0;
        pos[64 + t] = lo + tot0 + x1 - v1;
    }
    __syncthreads();
    if (t < 128) {
        int node = b * 128 + t;
        if (node <= NN) off[node] = pos[t];
    }
    // pass 2: write neigh at precomputed rank (no atomics)
    for (int i = lo + t; i < hi; i += 512) {
        int p = packed[i];
        int j = p >> 17;
        neigh[pos[j] + sl[i - lo]] = p & 0x1FFFF;
    }
}

// ---------------- layer 1: CSR mean-agg (d=3) + transform, fp16 out ----------------
__global__ __launch_bounds__(256) void k_l1(const int* __restrict__ off,
                                            const int* __restrict__ neigh,
                                            const float* __restrict__ x,
                                            const float* __restrict__ Wl,
                                            const float* __restrict__ bl,
                                            const float* __restrict__ Wr,
                                            _Float16* __restrict__ out) {
    int n = blockIdx.x * 4 + (threadIdx.x >> 6);
    int c = threadIdx.x & 63;
    if (n >= NN) return;
    int lo = off[n], hi = off[n + 1];
    float a0 = 0.f, a1 = 0.f, a2 = 0.f;
    for (int i = lo + c; i < hi; i += 64) {
        int s = neigh[i];
        a0 += x[s * 3 + 0];
        a1 += x[s * 3 + 1];
        a2 += x[s * 3 + 2];
    }
#pragma unroll
    for (int m = 1; m < 64; m <<= 1) {
        a0 += __shfl_xor(a0, m);
        a1 += __shfl_xor(a1, m);
        a2 += __shfl_xor(a2, m);
    }
    float ic = 1.0f / fmaxf((float)(hi - lo), 1.0f);
    a0 *= ic; a1 *= ic; a2 *= ic;
    float x0 = x[n * 3 + 0], x1 = x[n * 3 + 1], x2 = x[n * 3 + 2];
    float acc = bl[c]
              + a0 * Wl[0 * 64 + c] + a1 * Wl[1 * 64 + c] + a2 * Wl[2 * 64 + c]
              + x0 * Wr[0 * 64 + c] + x1 * Wr[1 * 64 + c] + x2 * Wr[2 * 64 + c];
    out[(size_t)n * 64 + c] = (_Float16)fmaxf(acc, 0.0f);
}

// ---------------- gather-only: quad-mode CSR mean (fp16 in/out) ----------------
__global__ __launch_bounds__(512, 8) void k_agg(const int* __restrict__ off,
                                                const int* __restrict__ neigh,
                                                const _Float16* __restrict__ h,
                                                _Float16* __restrict__ mean) {
    int li = threadIdx.x >> 6;
    int lane = threadIdx.x & 63;
    int g = lane >> 4;                    // neighbor slot within quad
    int q = lane & 15;                    // column quad (cols 4q..4q+3)
    int n = blockIdx.x * 8 + li;          // grid exact: 12500*8 = NN
    if (n >= NN) return;

    int lo = __builtin_amdgcn_readfirstlane(off[n]);
    int hi = __builtin_amdgcn_readfirstlane(off[n + 1]);
    int deg = hi - lo;
    const int* __restrict__ np = neigh + lo;
    const char* __restrict__ hb = (const char*)h;
    unsigned qoff = (unsigned)q << 3;

    float ax = 0.f, ay = 0.f, az = 0.f, aw = 0.f;
    int nq = deg >> 2;
#pragma unroll 4
    for (int i = 0; i < nq; ++i) {
        int s0 = np[4 * i + 0];           // uniform -> s_load
        int s1 = np[4 * i + 1];
        int s2 = np[4 * i + 2];
        int s3 = np[4 * i + 3];
        int s = (g & 2) ? ((g & 1) ? s3 : s2) : ((g & 1) ? s1 : s0);
        half4v v = *(const half4v*)(hb + (((unsigned)s << 7) | qoff));
        ax += (float)v.x; ay += (float)v.y; az += (float)v.z; aw += (float)v.w;
    }
    if (g == 0) {                         // tail: group 0 only
        for (int i = nq << 2; i < deg; ++i) {
            int s = np[i];
            half4v v = *(const half4v*)(hb + (((unsigned)s << 7) | qoff));
            ax += (float)v.x; ay += (float)v.y; az += (float)v.z; aw += (float)v.w;
        }
    }
#pragma unroll
    for (int m = 16; m <= 32; m <<= 1) {
        ax += __shfl_xor(ax, m);
        ay += __shfl_xor(ay, m);
        az += __shfl_xor(az, m);
        aw += __shfl_xor(aw, m);
    }
    if (g == 0) {
        float ic = 1.0f / fmaxf((float)deg, 1.0f);
        *(half4v*)&mean[(size_t)n * 64 + 4 * q] =
            half4v{(_Float16)(ax * ic), (_Float16)(ay * ic),
                   (_Float16)(az * ic), (_Float16)(aw * ic)};
    }
}

// ---------------- transform: [128 nodes][128]=[mean|root] x [128][64] via MFMA ----------------
__global__ __launch_bounds__(512) void k_xform(const _Float16* __restrict__ mean,
                                               const _Float16* __restrict__ h,
                                               const float* __restrict__ Wl,
                                               const float* __restrict__ bl,
                                               const float* __restrict__ Wr,
                                               _Float16* __restrict__ out) {
    __shared__ __align__(16) _Float16 A[128][136];   // 34.8 KiB, padded rows
    __shared__ __align__(16) _Float16 Wt[64][136];   // 17.4 KiB: W^T [c][kk], padded

    const int tid  = threadIdx.x;
    const int li   = tid >> 6;
    const int lane = tid & 63;
    const int g    = lane >> 4;
    const int q    = lane & 15;
    const int nb   = blockIdx.x * 128;

    // ---- stage Wt = [Wl;Wr]^T as f16 (coalesced f32 reads, once per block) ----
    for (int i = tid; i < 8192; i += 512) {
        int kk = i >> 6;       // 0..127
        int c  = i & 63;
        float w = (kk < 64) ? Wl[kk * 64 + c] : Wr[(kk - 64) * 64 + c];
        Wt[c][kk] = (_Float16)w;
    }

    // ---- stage A: thread t -> node tid>>2, 64B chunk tid&3 (mean|mean|root|root) ----
    {
        int n = tid >> 2, c = tid & 3;
        int gn = nb + n;
        if (gn >= NN) gn = NN - 1;                   // clamp (rows unused)
        const _Float16* srcp = (c < 2) ? &mean[(size_t)gn * 64 + (c & 1) * 32]
                                       : &h[(size_t)gn * 64 + (c & 1) * 32];
        half8v v0 = *(const half8v*)(srcp + 0);
        half8v v1 = *(const half8v*)(srcp + 8);
        half8v v2 = *(const half8v*)(srcp + 16);
        half8v v3 = *(const half8v*)(srcp + 24);
        _Float16* dstp = &A[n][(c >> 1) * 64 + (c & 1) * 32];
        *(half8v*)(dstp + 0)  = v0;
        *(half8v*)(dstp + 8)  = v1;
        *(half8v*)(dstp + 16) = v2;
        *(half8v*)(dstp + 24) = v3;
    }
    __syncthreads();

    // ---- B-frags from LDS: lane(g,q) tile t step s -> Wt[16t+q][32s+8g..+8] ----
    half8v bfr[4][4];
    float bias[4];
#pragma unroll
    for (int t = 0; t < 4; ++t) {
        bias[t] = bl[16 * t + q];
#pragma unroll
        for (int s = 0; s < 4; ++s)
            bfr[t][s] = *(const half8v*)&Wt[16 * t + q][32 * s + 8 * g];
    }

    // ---- A-frags: m = q (row 16*li+q), k = 32s + 8g + e ----
    const int row = 16 * li + q;
    half8v a0 = *(const half8v*)&A[row][0 * 32 + 8 * g];
    half8v a1 = *(const half8v*)&A[row][1 * 32 + 8 * g];
    half8v a2 = *(const half8v*)&A[row][2 * 32 + 8 * g];
    half8v a3 = *(const half8v*)&A[row][3 * 32 + 8 * g];

    f32x4 acc[4];
#pragma unroll
    for (int t = 0; t < 4; ++t) {
        acc[t] = f32x4{0.f, 0.f, 0.f, 0.f};
        acc[t] = __builtin_amdgcn_mfma_f32_16x16x32_f16(a0, bfr[t][0], acc[t], 0, 0, 0);
        acc[t] = __builtin_amdgcn_mfma_f32_16x16x32_f16(a1, bfr[t][1], acc[t], 0, 0, 0);
        acc[t] = __builtin_amdgcn_mfma_f32_16x16x32_f16(a2, bfr[t][2], acc[t], 0, 0, 0);
        acc[t] = __builtin_amdgcn_mfma_f32_16x16x32_f16(a3, bfr[t][3], acc[t], 0, 0, 0);
    }

    // ---- epilogue: C row (node) = g*4+r, col = 16t+q; bias + relu + fp16 store ----
#pragma unroll
    for (int t = 0; t < 4; ++t) {
        int col = 16 * t + q;
#pragma unroll
        for (int r = 0; r < 4; ++r) {
            int gn = nb + 16 * li + g * 4 + r;
            if (gn < NN) {
                float val = acc[t][r] + bias[t];
                out[(size_t)gn * 64 + col] = (_Float16)fmaxf(val, 0.0f);
            }
        }
    }
}

// ---------------- pooling helpers ----------------
__device__ __forceinline__ int lower_bound_batch(const int* __restrict__ batch, int val) {
    int lo = 0, hi = NN;
    while (lo < hi) {
        int mid = (lo + hi) >> 1;
        if (batch[mid] < val) lo = mid + 1; else hi = mid;
    }
    return lo;
}

__global__ __launch_bounds__(64) void k_pool(const _Float16* __restrict__ h,
                                             const int* __restrict__ batch,
                                             float* __restrict__ psum) {
    int g = blockIdx.x >> 5;
    int part = blockIdx.x & 31;
    int lane = threadIdx.x;
    int lo = lower_bound_batch(batch, g);
    int hi = lower_bound_batch(batch, g + 1);
    float s = 0.0f;
    for (int n = lo + part; n < hi; n += 32) s += (float)h[(size_t)n * 64 + lane];
    atomicAdd(&psum[g * 64 + lane], s);
}

__global__ __launch_bounds__(128) void k_fc(const float* __restrict__ psum,
                                            const int* __restrict__ batch,
                                            const float* __restrict__ Wfc,
                                            const float* __restrict__ bfc,
                                            float* __restrict__ out) {
    __shared__ float meanv[64];
    __shared__ float red[2];
    int g = blockIdx.x;
    int c = threadIdx.x;
    int lo = lower_bound_batch(batch, g);
    int hi = lower_bound_batch(batch, g + 1);
    float icnt = 1.0f / fmaxf((float)(hi - lo), 1.0f);
    if (c < 64) meanv[c] = psum[g * 64 + c] * icnt;
    __syncthreads();
    float acc = bfc[c];
#pragma unroll
    for (int k = 0; k < 64; ++k) acc += meanv[k] * Wfc[k * 128 + c];
    float ss = acc * acc;
#pragma unroll
    for (int off = 32; off; off >>= 1) ss += __shfl_down(ss, off);
    if ((c & 63) == 0) red[c >> 6] = ss;
    __syncthreads();
    float norm = fmaxf(sqrtf(red[0] + red[1]), 1e-12f);
    out[g * 128 + c] = acc / norm;
}

extern "C" void kernel_launch(void* const* d_in, const int* in_sizes, int n_in,
                              void* d_out, int out_size, void* d_ws, size_t ws_size,
                              hipStream_t stream) {
    const float* x    = (const float*)d_in[0];
    const int*   ei   = (const int*)d_in[1];
    const int*   src  = ei;
    const int*   dst  = ei + NE;
    const int*   batch = (const int*)d_in[2];
    const float* Wl1 = (const float*)d_in[3];
    const float* bl1 = (const float*)d_in[4];
    const float* Wr1 = (const float*)d_in[5];
    const float* Wl2 = (const float*)d_in[6];
    const float* bl2 = (const float*)d_in[7];
    const float* Wr2 = (const float*)d_in[8];
    const float* Wl3 = (const float*)d_in[9];
    const float* bl3 = (const float*)d_in[10];
    const float* Wr3 = (const float*)d_in[11];
    const float* Wl4 = (const float*)d_in[12];
    const float* bl4 = (const float*)d_in[13];
    const float* Wr4 = (const float*)d_in[14];
    const float* Wfc = (const float*)d_in[15];
    const float* bfc = (const float*)d_in[16];
    float* out = (float*)d_out;

    // workspace layout
    _Float16* hA   = (_Float16*)d_ws;                 // [N,64] fp16
    _Float16* hB   = hA + (size_t)NN * 64;            // [N,64] fp16
    _Float16* mnb  = hB + (size_t)NN * 64;            // [N,64] fp16 mean buffer
    float* psum    = (float*)(mnb + (size_t)NN * 64); // [G,64]
    int*   off     = (int*)(psum + (size_t)NG * 64);  // [N+1]
    int*   bb      = off + NN + 1;                    // [NB1+1]
    int*   rowtot  = bb + NB1 + 1;                    // [NB1]
    int*   rowbase = rowtot + NB1;                    // [NB1]
    int*   hist1   = rowbase + NB1;                   // [NB1*NBLK]
    int*   packed  = hist1 + NB1 * NBLK;              // [E]
    int*   neigh   = packed + NE;                     // [E]

    hipMemsetAsync(psum, 0, (size_t)NG * 64 * sizeof(float), stream);

    // CSR build: atomic-free two-level bucket sort, fully parallel scan
    k_hist<<<NBLK, 1024, 0, stream>>>(dst, hist1);
    k_rowsum<<<(NB1 + 3) / 4, 256, 0, stream>>>(hist1, rowtot);
    k_scanb<<<1, 832, 0, stream>>>(rowtot, rowbase, bb);
    k_rowscan<<<(NB1 + 3) / 4, 256, 0, stream>>>(hist1, rowbase);
    k_scat<<<NBLK, 1024, 0, stream>>>(src, dst, hist1, packed);
    k_bucket<<<NB1, 512, 0, stream>>>(packed, bb, neigh, off);

    // layer 1 (fused d=3 agg + transform), fp16 out
    k_l1<<<(NN + 3) / 4, 256, 0, stream>>>(off, neigh, x, Wl1, bl1, Wr1, hA);

    const int aggGrid = (NN + 7) / 8;
    const int xfGrid  = (NN + 127) / 128;

    // layers 2-4: gather-only + MFMA transform (ping-pong hA/hB)
    k_agg<<<aggGrid, 512, 0, stream>>>(off, neigh, hA, mnb);
    k_xform<<<xfGrid, 512, 0, stream>>>(mnb, hA, Wl2, bl2, Wr2, hB);

    k_agg<<<aggGrid, 512, 0, stream>>>(off, neigh, hB, mnb);
    k_xform<<<xfGrid, 512, 0, stream>>>(mnb, hB, Wl3, bl3, Wr3, hA);

    k_agg<<<aggGrid, 512, 0, stream>>>(off, neigh, hA, mnb);
    k_xform<<<xfGrid, 512, 0, stream>>>(mnb, hA, Wl4, bl4, Wr4, hB);

    k_pool<<<NG * 32, 64, 0, stream>>>(hB, batch, psum);
    k_fc<<<NG, 128, 0, stream>>>(psum, batch, Wfc, bfc, out);
}